// Round 10
// baseline (284.907 us; speedup 1.0000x reference)
//
#include <hip/hip_runtime.h>
#include <stdint.h>
#include <string.h>

#define N_USER 50000
#define N_ITEM 50000
#define N_EDGE 600000
#define D 128
#define NTOT 150000      // 3 * 50000 destination slots (uu | ub | iu)
#define ETOT 1800000
#define NB 293           // buckets = ceil(NTOT / SPAN)
#define BSH 9
#define SPAN 512         // slots per bucket
#define CHUNK 4096       // edges per block in bucket kernels (16/thread)

typedef unsigned short u16;
typedef unsigned int   u32;
typedef __attribute__((ext_vector_type(8))) short short8;   // 8 bf16 (MFMA A/B frag)
typedef __attribute__((ext_vector_type(4))) float floatx4;  // MFMA C/D frag

static __device__ __forceinline__ u16 f2b(float f) {        // f32 -> bf16 RNE
  u32 x; memcpy(&x, &f, 4);
  u32 r = x + 0x7fffu + ((x >> 16) & 1u);
  return (u16)(r >> 16);
}
static __device__ __forceinline__ float blo2f(u32 v) {
  u32 x = v << 16; float f; memcpy(&f, &x, 4); return f;
}
static __device__ __forceinline__ float bhi2f(u32 v) {
  u32 x = v & 0xffff0000u; float f; memcpy(&f, &x, 4); return f;
}

// ---- front: [0,440) edge-bucket histogram | [440,443) weight transpose (stacked) |
//      [443,2006) grid-stride f32->bf16 feature conversion (8 float4/thread) ----
// WTu = [W_uu ; W_iu]^T as [n=128][k=256]; WTi = W_ub^T as [n=128][k=128] at +32768 u16.
__global__ void __launch_bounds__(256) k_front(
    const int* __restrict__ duu, const int* __restrict__ dub, const int* __restrict__ diu,
    int* __restrict__ bhist,
    const float* __restrict__ W0, const float* __restrict__ W1, const float* __restrict__ W2,
    u16* __restrict__ WT,
    const float* __restrict__ fu, const float* __restrict__ fi,
    u16* __restrict__ fb_u, u16* __restrict__ fb_i) {
  int bid = blockIdx.x;
  if (bid < 440) {                       // bucket histogram
    __shared__ int h[NB];
    for (int i = threadIdx.x; i < NB; i += 256) h[i] = 0;
    __syncthreads();
    int base = bid * CHUNK;
    for (int j = threadIdx.x; j < CHUNK; j += 256) {
      int e = base + j;
      if (e < ETOT) {
        int t = e / N_EDGE, i = e - t * N_EDGE;
        int d = (t == 0) ? duu[i] : ((t == 1) ? dub[i] : diu[i]);
        atomicAdd(&h[(t * N_USER + d) >> BSH], 1);
      }
    }
    __syncthreads();
    for (int i = threadIdx.x; i < NB; i += 256) if (h[i]) atomicAdd(&bhist[i], h[i]);
  } else if (bid < 443) {                // weight transpose + bf16 (stacked layout)
    int wsel = bid - 440;
    for (int idx = threadIdx.x; idx < D * D; idx += 256) {
      int n = idx >> 7, k = idx & 127;
      if (wsel == 0)      WT[n * 256 + k]       = f2b(W0[k * D + n]);   // W_uu -> WTu k<128
      else if (wsel == 1) WT[n * 256 + 128 + k] = f2b(W2[k * D + n]);   // W_iu -> WTu k>=128
      else                WT[32768 + n * D + k] = f2b(W1[k * D + n]);   // W_ub -> WTi
    }
  } else {                               // feature conversion, grid-stride 8x float4
    int base = (bid - 443) * 2048;
#pragma unroll
    for (int u = 0; u < 8; ++u) {
      int gid = base + u * 256 + threadIdx.x;     // 3.2M float4 groups total
      if (gid < 3200000) {
        const float* src = fu; u16* dst = fb_u; int g = gid;
        if (g >= 1600000) { g -= 1600000; src = fi; dst = fb_i; }
        float4 v = ((const float4*)src)[g];
        union { u16 u[4]; uint2 d; } pk;
        pk.u[0] = f2b(v.x); pk.u[1] = f2b(v.y); pk.u[2] = f2b(v.z); pk.u[3] = f2b(v.w);
        ((uint2*)dst)[g] = pk.d;
      }
    }
  }
}

// ---- place edges into bucket-grouped ebuf; each block re-derives the bucket scan
//      (NB=293 > 256: 2-elements-per-thread 512-wide scan); block 0 publishes boff ----
__global__ void __launch_bounds__(256) k_bplace(
    const int* __restrict__ suu, const int* __restrict__ duu,
    const int* __restrict__ sub, const int* __restrict__ dub,
    const int* __restrict__ siu, const int* __restrict__ diu,
    const int* __restrict__ bhist, int* __restrict__ cursor,
    int* __restrict__ boff, u32* __restrict__ ebuf) {
  __shared__ int h[NB];
  __shared__ int sboff[NB];
  __shared__ int buf[256];
  int t = threadIdx.x;
  int a = (2 * t < NB) ? bhist[2 * t] : 0;
  int b = (2 * t + 1 < NB) ? bhist[2 * t + 1] : 0;
  buf[t] = a + b; __syncthreads();
  for (int s = 1; s < 256; s <<= 1) {
    int y = (t >= s) ? buf[t - s] : 0;
    __syncthreads(); buf[t] += y; __syncthreads();
  }
  int ex = buf[t] - (a + b);                 // exclusive prefix of pair base
  if (2 * t < NB) sboff[2 * t] = ex;
  if (2 * t + 1 < NB) sboff[2 * t + 1] = ex + a;
  if (blockIdx.x == 0) {
    if (2 * t < NB) boff[2 * t] = ex;
    if (2 * t + 1 < NB) boff[2 * t + 1] = ex + a;
    if (t == 255) boff[NB] = buf[255];       // total = ETOT
  }
  for (int i = t; i < NB; i += 256) h[i] = 0;
  __syncthreads();
  int base = blockIdx.x * CHUNK;
  u32 pay[16], br[16];
#pragma unroll
  for (int k = 0; k < 16; ++k) {
    int e = base + k * 256 + t;
    br[k] = 0xFFFFFFFFu;
    if (e < ETOT) {
      int ty = e / N_EDGE, i = e - ty * N_EDGE;
      int d, s;
      if (ty == 0)      { d = duu[i]; s = suu[i]; }
      else if (ty == 1) { d = dub[i]; s = sub[i]; }
      else              { d = diu[i]; s = siu[i]; }
      int slot = ty * N_USER + d;
      int bu = slot >> BSH;
      int rank = atomicAdd(&h[bu], 1);
      pay[k] = (u32)s | ((u32)(slot & (SPAN - 1)) << 16);
      br[k]  = (u32)bu | ((u32)rank << 9);       // bu<=292 fits 9 bits; rank<4096
    }
  }
  __syncthreads();
  for (int i = t; i < NB; i += 256)
    h[i] = sboff[i] + atomicAdd(&cursor[i], h[i]);    // block base within bucket region
  __syncthreads();
#pragma unroll
  for (int k = 0; k < 16; ++k) {
    if (br[k] != 0xFFFFFFFFu) {
      int bu = br[k] & 0x1FF, rank = (int)(br[k] >> 9);
      ebuf[h[bu] + rank] = pay[k];
    }
  }
}

// ---- per-bucket CSR finalize (SPAN=512, 2 slots/thread): off[] + ssrc[] ----
__global__ void __launch_bounds__(256) k_csr(const int* __restrict__ boff, const u32* __restrict__ ebuf,
                                             int* __restrict__ off, u16* __restrict__ ssrc) {
  __shared__ int sc[SPAN];
  __shared__ int so[SPAN];
  __shared__ int part[256];
  int b = blockIdx.x;
  int ebase = boff[b], ecnt = boff[b + 1] - ebase;
  int sbase = b << BSH;
  int nslots = (NTOT - sbase < SPAN) ? (NTOT - sbase) : SPAN;
  for (int i = threadIdx.x; i < SPAN; i += 256) sc[i] = 0;
  __syncthreads();
  for (int j = threadIdx.x; j < ecnt; j += 256)
    atomicAdd(&sc[ebuf[ebase + j] >> 16], 1);
  __syncthreads();
  int t = threadIdx.x;
  int s0 = sc[2 * t], s1 = sc[2 * t + 1];
  int tsum = s0 + s1;
  part[t] = tsum; __syncthreads();
  for (int s = 1; s < 256; s <<= 1) {
    int y = (t >= s) ? part[t - s] : 0;
    __syncthreads(); part[t] += y; __syncthreads();
  }
  int pbase = part[t] - tsum;
  so[2 * t]     = pbase;
  so[2 * t + 1] = pbase + s0;
  __syncthreads();
  for (int i = threadIdx.x; i < nslots; i += 256)
    off[sbase + i] = ebase + so[i];
  if (b == 0 && threadIdx.x == 0) off[NTOT] = ETOT;
  for (int i = threadIdx.x; i < SPAN; i += 256) sc[i] = so[i];   // cursors
  __syncthreads();
  for (int j = threadIdx.x; j < ecnt; j += 256) {
    u32 p = ebuf[ebase + j];
    int pos = atomicAdd(&sc[p >> 16], 1);
    ssrc[ebase + pos] = (u16)(p & 0xFFFFu);
  }
}

// ---- gather-mean v4: HALF-wave (32 lanes) per slot; TWO edges per VMEM instruction.
//      Lanes 0-15 carry even edge, 16-31 odd edge; each lane loads uint4 (16B) of its
//      edge's row (16 lanes x 16B = 256B/row, 2 rows/instr). Edge srcs preloaded and
//      broadcast via __shfl. Parity partial sums merged by shfl_xor(16) at the end.
//      (Summation-order change is the r3-verified group-split pattern.) ----
__global__ void __launch_bounds__(256) k_mean(const u16* __restrict__ fb_u, const u16* __restrict__ fb_i,
                                              const int* __restrict__ off, const u16* __restrict__ ssrc,
                                              u16* __restrict__ ob) {
  int slot = blockIdx.x * 8 + (threadIdx.x >> 5);
  int lane = threadIdx.x & 31;
  int par = lane >> 4;               // edge parity (0: even edges, 1: odd edges)
  int l16 = lane & 15;               // column group: bf16 cols [l16*8, l16*8+8)
  if (slot >= NTOT) return;
  int t = slot / N_USER;
  int d = slot - t * N_USER;
  const u16* fb = (t == 2) ? fb_i : fb_u;
  int s = off[slot], e = off[slot + 1];
  int n = e - s;
  int my_src = (lane < n) ? (int)ssrc[s + lane] : 0;   // preload up to 32 edge srcs
  float a0 = 0.f, a1 = 0.f, a2 = 0.f, a3 = 0.f, a4 = 0.f, a5 = 0.f, a6 = 0.f, a7 = 0.f;
  int m = (n < 32) ? n : 32;
  for (int i = 0; i < m; i += 2) {
    int e0 = i + par;
    bool ok = e0 < m;
    int sr = __shfl(my_src, ok ? e0 : i, 32);
    uint4 v = ((const uint4*)(fb + (size_t)sr * D))[l16];
    if (ok) {
      a0 += blo2f(v.x); a1 += bhi2f(v.x);
      a2 += blo2f(v.y); a3 += bhi2f(v.y);
      a4 += blo2f(v.z); a5 += bhi2f(v.z);
      a6 += blo2f(v.w); a7 += bhi2f(v.w);
    }
  }
  for (int j = s + 32 + par; j < e; j += 2) {   // rare degree>32 remainder (paired)
    int sr = ssrc[j];
    uint4 v = ((const uint4*)(fb + (size_t)sr * D))[l16];
    a0 += blo2f(v.x); a1 += bhi2f(v.x);
    a2 += blo2f(v.y); a3 += bhi2f(v.y);
    a4 += blo2f(v.z); a5 += bhi2f(v.z);
    a6 += blo2f(v.w); a7 += bhi2f(v.w);
  }
  // merge parity partials (lane j gets lane j+16's sums)
  a0 += __shfl_xor(a0, 16, 32); a1 += __shfl_xor(a1, 16, 32);
  a2 += __shfl_xor(a2, 16, 32); a3 += __shfl_xor(a3, 16, 32);
  a4 += __shfl_xor(a4, 16, 32); a5 += __shfl_xor(a5, 16, 32);
  a6 += __shfl_xor(a6, 16, 32); a7 += __shfl_xor(a7, 16, 32);
  if (par == 0) {
    float inv = (n > 0) ? 1.0f / (float)n : 0.f;
    uint4 pk;
    pk.x = (u32)f2b(a0 * inv) | ((u32)f2b(a1 * inv) << 16);
    pk.y = (u32)f2b(a2 * inv) | ((u32)f2b(a3 * inv) << 16);
    pk.z = (u32)f2b(a4 * inv) | ((u32)f2b(a5 * inv) << 16);
    pk.w = (u32)f2b(a6 * inv) | ((u32)f2b(a7 * inv) << 16);
    u32* mrow;
    if (t == 0)      mrow = (u32*)(ob + (size_t)d * 256);              // mean_uu: row 1st half
    else if (t == 2) mrow = (u32*)(ob + (size_t)d * 256 + 128);        // mean_iu: row 2nd half
    else             mrow = (u32*)(ob + 12800000 + (size_t)d * 256);   // mean_ub: item row
    ((uint4*)mrow)[l16] = pk;
  }
}

// ---- final GEMM v4: LDS-staged B fragments + ALL A-fragment and gate loads hoisted
//      BEFORE the barrier (HBM latency overlaps staging; __syncthreads drains them).
//      MFMA loop is then pure LDS+MFMA. 2 row-tiles (32 rows) per wave. ----
__global__ void __launch_bounds__(256, 2) k_out(float* out, const u16* __restrict__ WT,
                                                const float* __restrict__ buu, const float* __restrict__ bub,
                                                const float* __restrict__ biu, const int* __restrict__ off) {
  int users = (blockIdx.y == 0);
  int tid = threadIdx.x;
  int w = tid >> 6, lane = tid & 63, quad = lane >> 4, l16 = lane & 15;
  int KT = users ? 8 : 4;                        // K/32 tiles (K=256 user, 128 item)
  const u16* Wsrc = users ? WT : (WT + 32768);
  int wstride = users ? 256 : 128;               // u16 per WT row

  // stage B fragments: sB[((kk*8+nt)*64+lane)*8 u16] = 16B fragment for (kk,nt,lane)
  __shared__ u16 sB[32768];                      // 64 KB (user); item uses first 32 KB
  int nfrag = KT * 8 * 64;
  for (int fid = tid; fid < nfrag; fid += 256) {
    int fl = fid & 63, fnt = (fid >> 6) & 7, fkk = fid >> 9;
    int fq = fl >> 4, fl16 = fl & 15;
    const u16* src = Wsrc + (fnt * 16 + fl16) * wstride + fkk * 32 + fq * 8;
    *(uint4*)(sB + (size_t)fid * 8) = *(const uint4*)src;
  }

  int row0 = blockIdx.x * 128 + w * 32;          // wave's 32 rows (2 tiles of 16)
  const u16* ob = (const u16*)out;
  const u16* Abase = users ? ob : (ob + 12800000);
  size_t outoff = users ? 0 : (size_t)N_USER;

  int r0a = row0 + l16, r1a = row0 + 16 + l16;
  int rA0 = r0a < N_USER ? r0a : N_USER - 1;
  int rA1 = r1a < N_USER ? r1a : N_USER - 1;
  const u16* A0 = Abase + (size_t)rA0 * 256 + quad * 8;
  const u16* A1 = Abase + (size_t)rA1 * 256 + quad * 8;

  // hoist all A-fragment loads (issued before the barrier drains VMEM)
  short8 af0[8], af1[8];
#pragma unroll
  for (int kk = 0; kk < 8; ++kk) {
    if (kk < KT) {
      af0[kk] = *(const short8*)(A0 + kk * 32);
      af1[kk] = *(const short8*)(A1 + kk * 32);
    }
  }
  // hoist degree-gate loads too
  int nA[2][4], nB[2][4];
#pragma unroll
  for (int rt = 0; rt < 2; ++rt)
#pragma unroll
    for (int i = 0; i < 4; ++i) {
      int grow = row0 + rt * 16 + quad * 4 + i;
      bool ok = grow < N_USER;
      if (users) {
        nA[rt][i] = ok ? (off[grow + 1] - off[grow]) : 0;                             // uu
        nB[rt][i] = ok ? (off[2 * N_USER + grow + 1] - off[2 * N_USER + grow]) : 0;   // iu
      } else {
        nA[rt][i] = ok ? (off[N_USER + grow + 1] - off[N_USER + grow]) : 0;           // ub
        nB[rt][i] = 0;
      }
    }
  __syncthreads();

  floatx4 acc[2][8];
#pragma unroll
  for (int rt = 0; rt < 2; ++rt)
#pragma unroll
    for (int nt = 0; nt < 8; ++nt) acc[rt][nt] = (floatx4){0.f, 0.f, 0.f, 0.f};

#pragma unroll
  for (int kk = 0; kk < 8; ++kk) {
    if (kk < KT) {
      const short8* bp = (const short8*)(sB + ((size_t)kk * 512 + lane) * 8);
#pragma unroll
      for (int nt = 0; nt < 8; ++nt) {
        short8 bf = bp[nt * 64];
        acc[0][nt] = __builtin_amdgcn_mfma_f32_16x16x32_bf16(af0[kk], bf, acc[0][nt], 0, 0, 0);
        acc[1][nt] = __builtin_amdgcn_mfma_f32_16x16x32_bf16(af1[kk], bf, acc[1][nt], 0, 0, 0);
      }
    }
  }

#pragma unroll
  for (int rt = 0; rt < 2; ++rt) {
    int tbase = row0 + rt * 16;
#pragma unroll
    for (int nt = 0; nt < 8; ++nt) {
      int col = nt * 16 + l16;
      float bA = users ? buu[col] : bub[col];
      float bB = users ? biu[col] : 0.f;
#pragma unroll
      for (int i = 0; i < 4; ++i) {
        int grow = tbase + quad * 4 + i;
        if (grow < N_USER) {
          float r = acc[rt][nt][i] + (nA[rt][i] > 0 ? bA : 0.f) + (nB[rt][i] > 0 ? bB : 0.f);
          out[(outoff + (size_t)grow) * D + col] = r;
        }
      }
    }
  }
}

extern "C" void kernel_launch(void* const* d_in, const int* in_sizes, int n_in,
                              void* d_out, int out_size, void* d_ws, size_t ws_size,
                              hipStream_t stream) {
  const float* fu  = (const float*)d_in[0];
  const float* fi  = (const float*)d_in[1];
  const float* Wuu = (const float*)d_in[2];
  const float* buu = (const float*)d_in[3];
  const float* Wub = (const float*)d_in[4];
  const float* bub = (const float*)d_in[5];
  const float* Wiu = (const float*)d_in[6];
  const float* biu = (const float*)d_in[7];
  const int* suu = (const int*)d_in[8];
  const int* duu = (const int*)d_in[9];
  const int* sub = (const int*)d_in[10];
  const int* dub = (const int*)d_in[11];
  const int* siu = (const int*)d_in[12];
  const int* diu = (const int*)d_in[13];
  float* out = (float*)d_out;   // f32: [out_user 50000x128 | out_item 50000x128]
  u16* ob = (u16*)d_out;
  // d_out scratch (race-free): k_mean writes bf16 means INTO the output rows
  //   user row r: [0,256B)=mean_uu, [256B,512B)=mean_iu ; item row r: [0,256B)=mean_ub
  // k_out waves read only their own rows' means (used values), then overwrite them.

  // workspace layout (37.1 MB), offsets in INTs:
  //   off 150016 | bhist 320 | cursor 320 | boff 320 | ebuf 1.8M | ssrc 900000 |
  //   WT 24576 | fb_u 3.2M | fb_i 3.2M  -> ends at 9,275,552 ints
  int* wsi    = (int*)d_ws;
  int* off    = wsi;                        // [150001] -> pad to 150016
  int* bhist  = wsi + 150016;               // [293] pad 320
  int* cursor = wsi + 150336;               // [293] pad 320
  int* boff   = wsi + 150656;               // [294] pad 320
  u32* ebuf   = (u32*)(wsi + 150976);       // [1800000] (7.2 MB)
  u16* ssrc   = (u16*)(wsi + 1950976);      // [1800000] u16 (3.6 MB)
  u16* WT     = (u16*)(wsi + 2850976);      // WTu 32768 + WTi 16384 u16 (96 KB)
  u16* fb_u   = (u16*)(wsi + 2875552);      // 50000x128 bf16 row-major (12.8 MB)
  u16* fb_i   = (u16*)(wsi + 6075552);      // 50000x128 bf16 row-major (12.8 MB)

  hipMemsetAsync(bhist, 0, 640 * sizeof(int), stream);   // bhist + cursor
  k_front<<<443 + 1563, 256, 0, stream>>>(duu, dub, diu, bhist, Wuu, Wub, Wiu, WT,
                                          fu, fi, fb_u, fb_i);
  k_bplace<<<440, 256, 0, stream>>>(suu, duu, sub, dub, siu, diu, bhist, cursor, boff, ebuf);
  k_csr<<<NB, 256, 0, stream>>>(boff, ebuf, off, ssrc);
  k_mean<<<18750, 256, 0, stream>>>(fb_u, fb_i, off, ssrc, ob);
  k_out<<<dim3(391, 2), 256, 0, stream>>>(out, WT, buu, bub, biu, off);
}

// Round 12
// 272.698 us; speedup vs baseline: 1.0448x; 1.0448x over previous
//
#include <hip/hip_runtime.h>
#include <stdint.h>
#include <string.h>

#define N_USER 50000
#define N_ITEM 50000
#define N_EDGE 600000
#define D 128
#define NTOT 150000      // 3 * 50000 destination slots (uu | ub | iu)
#define ETOT 1800000
#define NB 293           // buckets = ceil(NTOT / SPAN)
#define BSH 9
#define SPAN 512         // slots per bucket
#define CHUNK 4096       // edges per block in bucket kernels (16/thread)

typedef unsigned short u16;
typedef unsigned int   u32;
typedef __attribute__((ext_vector_type(8))) short short8;   // 8 bf16 (MFMA A/B frag)
typedef __attribute__((ext_vector_type(4))) float floatx4;  // MFMA C/D frag

static __device__ __forceinline__ u16 f2b(float f) {        // f32 -> bf16 RNE
  u32 x; memcpy(&x, &f, 4);
  u32 r = x + 0x7fffu + ((x >> 16) & 1u);
  return (u16)(r >> 16);
}
static __device__ __forceinline__ float blo2f(u32 v) {
  u32 x = v << 16; float f; memcpy(&f, &x, 4); return f;
}
static __device__ __forceinline__ float bhi2f(u32 v) {
  u32 x = v & 0xffff0000u; float f; memcpy(&f, &x, 4); return f;
}

// shared streaming f32->bf16 conversion body: 8 float4-groups per thread starting
// at group cbase. Total groups = 3.2M (fu then fi). Runs as filler blocks inside
// the under-utilized k_bplace/k_csr launches (440 / 293 real blocks on 256 CUs).
static __device__ __forceinline__ void conv_chunk(int cbase,
    const float* __restrict__ fu, const float* __restrict__ fi,
    u16* __restrict__ fb_u, u16* __restrict__ fb_i) {
#pragma unroll
  for (int u = 0; u < 8; ++u) {
    int gid = cbase + u * 256 + (int)threadIdx.x;
    if (gid < 3200000) {
      const float* src = fu; u16* dst = fb_u; int g = gid;
      if (g >= 1600000) { g -= 1600000; src = fi; dst = fb_i; }
      float4 v = ((const float4*)src)[g];
      union { u16 q[4]; uint2 d; } pk;
      pk.q[0] = f2b(v.x); pk.q[1] = f2b(v.y); pk.q[2] = f2b(v.z); pk.q[3] = f2b(v.w);
      ((uint2*)dst)[g] = pk.d;
    }
  }
}

// ---- front: [0,440) edge-bucket histogram | [440,443) weight transpose (stacked) ----
// WTu = [W_uu ; W_iu]^T as [n=128][k=256]; WTi = W_ub^T as [n=128][k=128] at +32768 u16.
__global__ void __launch_bounds__(256) k_front(
    const int* __restrict__ duu, const int* __restrict__ dub, const int* __restrict__ diu,
    int* __restrict__ bhist,
    const float* __restrict__ W0, const float* __restrict__ W1, const float* __restrict__ W2,
    u16* __restrict__ WT) {
  int bid = blockIdx.x;
  if (bid < 440) {                       // bucket histogram
    __shared__ int h[NB];
    for (int i = threadIdx.x; i < NB; i += 256) h[i] = 0;
    __syncthreads();
    int base = bid * CHUNK;
    for (int j = threadIdx.x; j < CHUNK; j += 256) {
      int e = base + j;
      if (e < ETOT) {
        int t = e / N_EDGE, i = e - t * N_EDGE;
        int d = (t == 0) ? duu[i] : ((t == 1) ? dub[i] : diu[i]);
        atomicAdd(&h[(t * N_USER + d) >> BSH], 1);
      }
    }
    __syncthreads();
    for (int i = threadIdx.x; i < NB; i += 256) if (h[i]) atomicAdd(&bhist[i], h[i]);
  } else {                               // weight transpose + bf16 (stacked layout)
    int wsel = bid - 440;
    for (int idx = threadIdx.x; idx < D * D; idx += 256) {
      int n = idx >> 7, k = idx & 127;
      if (wsel == 0)      WT[n * 256 + k]       = f2b(W0[k * D + n]);   // W_uu -> WTu k<128
      else if (wsel == 1) WT[n * 256 + 128 + k] = f2b(W2[k * D + n]);   // W_iu -> WTu k>=128
      else                WT[32768 + n * D + k] = f2b(W1[k * D + n]);   // W_ub -> WTi
    }
  }
}

// ---- place edges into bucket-grouped ebuf; blocks >=440 run feature conversion
//      (part 1: groups [0, 1601536)). Each placement block re-derives the bucket
//      scan from bhist; block 0 publishes boff ----
__global__ void __launch_bounds__(256) k_bplace(
    const int* __restrict__ suu, const int* __restrict__ duu,
    const int* __restrict__ sub, const int* __restrict__ dub,
    const int* __restrict__ siu, const int* __restrict__ diu,
    const int* __restrict__ bhist, int* __restrict__ cursor,
    int* __restrict__ boff, u32* __restrict__ ebuf,
    const float* __restrict__ fu, const float* __restrict__ fi,
    u16* __restrict__ fb_u, u16* __restrict__ fb_i) {
  if (blockIdx.x >= 440) {               // conversion filler (idle-CU work)
    conv_chunk((blockIdx.x - 440) * 2048, fu, fi, fb_u, fb_i);
    return;
  }
  __shared__ int h[NB];
  __shared__ int sboff[NB];
  __shared__ int buf[256];
  int t = threadIdx.x;
  int a = (2 * t < NB) ? bhist[2 * t] : 0;
  int b = (2 * t + 1 < NB) ? bhist[2 * t + 1] : 0;
  buf[t] = a + b; __syncthreads();
  for (int s = 1; s < 256; s <<= 1) {
    int y = (t >= s) ? buf[t - s] : 0;
    __syncthreads(); buf[t] += y; __syncthreads();
  }
  int ex = buf[t] - (a + b);                 // exclusive prefix of pair base
  if (2 * t < NB) sboff[2 * t] = ex;
  if (2 * t + 1 < NB) sboff[2 * t + 1] = ex + a;
  if (blockIdx.x == 0) {
    if (2 * t < NB) boff[2 * t] = ex;
    if (2 * t + 1 < NB) boff[2 * t + 1] = ex + a;
    if (t == 255) boff[NB] = buf[255];       // total = ETOT
  }
  for (int i = t; i < NB; i += 256) h[i] = 0;
  __syncthreads();
  int base = blockIdx.x * CHUNK;
  u32 pay[16], br[16];
#pragma unroll
  for (int k = 0; k < 16; ++k) {
    int e = base + k * 256 + t;
    br[k] = 0xFFFFFFFFu;
    if (e < ETOT) {
      int ty = e / N_EDGE, i = e - ty * N_EDGE;
      int d, s;
      if (ty == 0)      { d = duu[i]; s = suu[i]; }
      else if (ty == 1) { d = dub[i]; s = sub[i]; }
      else              { d = diu[i]; s = siu[i]; }
      int slot = ty * N_USER + d;
      int bu = slot >> BSH;
      int rank = atomicAdd(&h[bu], 1);
      pay[k] = (u32)s | ((u32)(slot & (SPAN - 1)) << 16);
      br[k]  = (u32)bu | ((u32)rank << 9);       // bu<=292 fits 9 bits; rank<4096
    }
  }
  __syncthreads();
  for (int i = t; i < NB; i += 256)
    h[i] = sboff[i] + atomicAdd(&cursor[i], h[i]);    // block base within bucket region
  __syncthreads();
#pragma unroll
  for (int k = 0; k < 16; ++k) {
    if (br[k] != 0xFFFFFFFFu) {
      int bu = br[k] & 0x1FF, rank = (int)(br[k] >> 9);
      ebuf[h[bu] + rank] = pay[k];
    }
  }
}

// ---- per-bucket CSR finalize (SPAN=512, 2 slots/thread); blocks >=293 run
//      feature conversion part 2 (groups [1601536, 3200000)) ----
__global__ void __launch_bounds__(256) k_csr(const int* __restrict__ boff, const u32* __restrict__ ebuf,
                                             int* __restrict__ off, u16* __restrict__ ssrc,
                                             const float* __restrict__ fu, const float* __restrict__ fi,
                                             u16* __restrict__ fb_u, u16* __restrict__ fb_i) {
  if (blockIdx.x >= NB) {                // conversion filler (idle-CU work)
    conv_chunk((blockIdx.x - NB) * 2048 + 1601536, fu, fi, fb_u, fb_i);
    return;
  }
  __shared__ int sc[SPAN];
  __shared__ int so[SPAN];
  __shared__ int part[256];
  int b = blockIdx.x;
  int ebase = boff[b], ecnt = boff[b + 1] - ebase;
  int sbase = b << BSH;
  int nslots = (NTOT - sbase < SPAN) ? (NTOT - sbase) : SPAN;
  for (int i = threadIdx.x; i < SPAN; i += 256) sc[i] = 0;
  __syncthreads();
  for (int j = threadIdx.x; j < ecnt; j += 256)
    atomicAdd(&sc[ebuf[ebase + j] >> 16], 1);
  __syncthreads();
  int t = threadIdx.x;
  int s0 = sc[2 * t], s1 = sc[2 * t + 1];
  int tsum = s0 + s1;
  part[t] = tsum; __syncthreads();
  for (int s = 1; s < 256; s <<= 1) {
    int y = (t >= s) ? part[t - s] : 0;
    __syncthreads(); part[t] += y; __syncthreads();
  }
  int pbase = part[t] - tsum;
  so[2 * t]     = pbase;
  so[2 * t + 1] = pbase + s0;
  __syncthreads();
  for (int i = threadIdx.x; i < nslots; i += 256)
    off[sbase + i] = ebase + so[i];
  if (b == 0 && threadIdx.x == 0) off[NTOT] = ETOT;
  for (int i = threadIdx.x; i < SPAN; i += 256) sc[i] = so[i];   // cursors
  __syncthreads();
  for (int j = threadIdx.x; j < ecnt; j += 256) {
    u32 p = ebuf[ebase + j];
    int pos = atomicAdd(&sc[p >> 16], 1);
    ssrc[ebase + pos] = (u16)(p & 0xFFFFu);
  }
}

// ---- gather-mean v5 (= proven v3 + deeper MLP): HALF-wave (32 lanes) per slot,
//      uint2 (8B) per lane per row; edge srcs preloaded once and broadcast via
//      __shfl; 8-deep load batch (8 independent VMEM ops in flight), then 4/1
//      remainders. Degree>32 falls back to direct loads. ----
__global__ void __launch_bounds__(256) k_mean(const u16* __restrict__ fb_u, const u16* __restrict__ fb_i,
                                              const int* __restrict__ off, const u16* __restrict__ ssrc,
                                              u16* __restrict__ ob) {
  int slot = blockIdx.x * 8 + (threadIdx.x >> 5);
  int lane = threadIdx.x & 31;
  if (slot >= NTOT) return;
  int t = slot / N_USER;
  int d = slot - t * N_USER;
  const u16* fb = (t == 2) ? fb_i : fb_u;
  int s = off[slot], e = off[slot + 1];
  int n = e - s;
  int my_src = (lane < n) ? (int)ssrc[s + lane] : 0;   // preload up to 32 edge srcs
  float a0 = 0.f, a1 = 0.f, a2 = 0.f, a3 = 0.f;
  int m = (n < 32) ? n : 32;
  int i = 0;
  for (; i + 8 <= m; i += 8) {
    int sA[8];
#pragma unroll
    for (int k = 0; k < 8; ++k) sA[k] = __shfl(my_src, i + k, 32);
    uint2 v[8];
#pragma unroll
    for (int k = 0; k < 8; ++k) v[k] = ((const uint2*)(fb + (size_t)sA[k] * D))[lane];
#pragma unroll
    for (int k = 0; k < 8; ++k) {
      a0 += blo2f(v[k].x); a1 += bhi2f(v[k].x);
      a2 += blo2f(v[k].y); a3 += bhi2f(v[k].y);
    }
  }
  for (; i + 4 <= m; i += 4) {
    int s0 = __shfl(my_src, i, 32);
    int s1 = __shfl(my_src, i + 1, 32);
    int s2 = __shfl(my_src, i + 2, 32);
    int s3 = __shfl(my_src, i + 3, 32);
    uint2 v0 = ((const uint2*)(fb + (size_t)s0 * D))[lane];
    uint2 v1 = ((const uint2*)(fb + (size_t)s1 * D))[lane];
    uint2 v2 = ((const uint2*)(fb + (size_t)s2 * D))[lane];
    uint2 v3 = ((const uint2*)(fb + (size_t)s3 * D))[lane];
    a0 += blo2f(v0.x) + blo2f(v1.x) + blo2f(v2.x) + blo2f(v3.x);
    a1 += bhi2f(v0.x) + bhi2f(v1.x) + bhi2f(v2.x) + bhi2f(v3.x);
    a2 += blo2f(v0.y) + blo2f(v1.y) + blo2f(v2.y) + blo2f(v3.y);
    a3 += bhi2f(v0.y) + bhi2f(v1.y) + bhi2f(v2.y) + bhi2f(v3.y);
  }
  for (; i < m; ++i) {
    int sr = __shfl(my_src, i, 32);
    uint2 v = ((const uint2*)(fb + (size_t)sr * D))[lane];
    a0 += blo2f(v.x); a1 += bhi2f(v.x);
    a2 += blo2f(v.y); a3 += bhi2f(v.y);
  }
  for (int j = s + 32; j < e; ++j) {     // rare degree>32 remainder
    int sr = ssrc[j];
    uint2 v = ((const uint2*)(fb + (size_t)sr * D))[lane];
    a0 += blo2f(v.x); a1 += bhi2f(v.x);
    a2 += blo2f(v.y); a3 += bhi2f(v.y);
  }
  float inv = (n > 0) ? 1.0f / (float)n : 0.f;
  u32 p0 = (u32)f2b(a0 * inv) | ((u32)f2b(a1 * inv) << 16);
  u32 p1 = (u32)f2b(a2 * inv) | ((u32)f2b(a3 * inv) << 16);
  u32* mrow;
  if (t == 0)      mrow = (u32*)(ob + (size_t)d * 256);              // mean_uu: row 1st half
  else if (t == 2) mrow = (u32*)(ob + (size_t)d * 256 + 128);        // mean_iu: row 2nd half
  else             mrow = (u32*)(ob + 12800000 + (size_t)d * 256);   // mean_ub: item row
  ((uint2*)mrow)[lane] = make_uint2(p0, p1);
}

// ---- final GEMM v4: LDS-staged B fragments + ALL A-fragment and gate loads hoisted
//      BEFORE the barrier (HBM latency overlaps staging; __syncthreads drains them).
//      MFMA loop is then pure LDS+MFMA. 2 row-tiles (32 rows) per wave. ----
__global__ void __launch_bounds__(256, 2) k_out(float* out, const u16* __restrict__ WT,
                                                const float* __restrict__ buu, const float* __restrict__ bub,
                                                const float* __restrict__ biu, const int* __restrict__ off) {
  int users = (blockIdx.y == 0);
  int tid = threadIdx.x;
  int w = tid >> 6, lane = tid & 63, quad = lane >> 4, l16 = lane & 15;
  int KT = users ? 8 : 4;                        // K/32 tiles (K=256 user, 128 item)
  const u16* Wsrc = users ? WT : (WT + 32768);
  int wstride = users ? 256 : 128;               // u16 per WT row

  // stage B fragments: sB[((kk*8+nt)*64+lane)*8 u16] = 16B fragment for (kk,nt,lane)
  __shared__ u16 sB[32768];                      // 64 KB (user); item uses first 32 KB
  int nfrag = KT * 8 * 64;
  for (int fid = tid; fid < nfrag; fid += 256) {
    int fl = fid & 63, fnt = (fid >> 6) & 7, fkk = fid >> 9;
    int fq = fl >> 4, fl16 = fl & 15;
    const u16* src = Wsrc + (fnt * 16 + fl16) * wstride + fkk * 32 + fq * 8;
    *(uint4*)(sB + (size_t)fid * 8) = *(const uint4*)src;
  }

  int row0 = blockIdx.x * 128 + w * 32;          // wave's 32 rows (2 tiles of 16)
  const u16* ob = (const u16*)out;
  const u16* Abase = users ? ob : (ob + 12800000);
  size_t outoff = users ? 0 : (size_t)N_USER;

  int r0a = row0 + l16, r1a = row0 + 16 + l16;
  int rA0 = r0a < N_USER ? r0a : N_USER - 1;
  int rA1 = r1a < N_USER ? r1a : N_USER - 1;
  const u16* A0 = Abase + (size_t)rA0 * 256 + quad * 8;
  const u16* A1 = Abase + (size_t)rA1 * 256 + quad * 8;

  // hoist all A-fragment loads (issued before the barrier drains VMEM)
  short8 af0[8], af1[8];
#pragma unroll
  for (int kk = 0; kk < 8; ++kk) {
    if (kk < KT) {
      af0[kk] = *(const short8*)(A0 + kk * 32);
      af1[kk] = *(const short8*)(A1 + kk * 32);
    }
  }
  // hoist degree-gate loads too
  int nA[2][4], nB[2][4];
#pragma unroll
  for (int rt = 0; rt < 2; ++rt)
#pragma unroll
    for (int i = 0; i < 4; ++i) {
      int grow = row0 + rt * 16 + quad * 4 + i;
      bool ok = grow < N_USER;
      if (users) {
        nA[rt][i] = ok ? (off[grow + 1] - off[grow]) : 0;                             // uu
        nB[rt][i] = ok ? (off[2 * N_USER + grow + 1] - off[2 * N_USER + grow]) : 0;   // iu
      } else {
        nA[rt][i] = ok ? (off[N_USER + grow + 1] - off[N_USER + grow]) : 0;           // ub
        nB[rt][i] = 0;
      }
    }
  __syncthreads();

  floatx4 acc[2][8];
#pragma unroll
  for (int rt = 0; rt < 2; ++rt)
#pragma unroll
    for (int nt = 0; nt < 8; ++nt) acc[rt][nt] = (floatx4){0.f, 0.f, 0.f, 0.f};

#pragma unroll
  for (int kk = 0; kk < 8; ++kk) {
    if (kk < KT) {
      const short8* bp = (const short8*)(sB + ((size_t)kk * 512 + lane) * 8);
#pragma unroll
      for (int nt = 0; nt < 8; ++nt) {
        short8 bf = bp[nt * 64];
        acc[0][nt] = __builtin_amdgcn_mfma_f32_16x16x32_bf16(af0[kk], bf, acc[0][nt], 0, 0, 0);
        acc[1][nt] = __builtin_amdgcn_mfma_f32_16x16x32_bf16(af1[kk], bf, acc[1][nt], 0, 0, 0);
      }
    }
  }

#pragma unroll
  for (int rt = 0; rt < 2; ++rt) {
    int tbase = row0 + rt * 16;
#pragma unroll
    for (int nt = 0; nt < 8; ++nt) {
      int col = nt * 16 + l16;
      float bA = users ? buu[col] : bub[col];
      float bB = users ? biu[col] : 0.f;
#pragma unroll
      for (int i = 0; i < 4; ++i) {
        int grow = tbase + quad * 4 + i;
        if (grow < N_USER) {
          float r = acc[rt][nt][i] + (nA[rt][i] > 0 ? bA : 0.f) + (nB[rt][i] > 0 ? bB : 0.f);
          out[(outoff + (size_t)grow) * D + col] = r;
        }
      }
    }
  }
}

extern "C" void kernel_launch(void* const* d_in, const int* in_sizes, int n_in,
                              void* d_out, int out_size, void* d_ws, size_t ws_size,
                              hipStream_t stream) {
  const float* fu  = (const float*)d_in[0];
  const float* fi  = (const float*)d_in[1];
  const float* Wuu = (const float*)d_in[2];
  const float* buu = (const float*)d_in[3];
  const float* Wub = (const float*)d_in[4];
  const float* bub = (const float*)d_in[5];
  const float* Wiu = (const float*)d_in[6];
  const float* biu = (const float*)d_in[7];
  const int* suu = (const int*)d_in[8];
  const int* duu = (const int*)d_in[9];
  const int* sub = (const int*)d_in[10];
  const int* dub = (const int*)d_in[11];
  const int* siu = (const int*)d_in[12];
  const int* diu = (const int*)d_in[13];
  float* out = (float*)d_out;   // f32: [out_user 50000x128 | out_item 50000x128]
  u16* ob = (u16*)d_out;
  // d_out scratch (race-free): k_mean writes bf16 means INTO the output rows
  //   user row r: [0,256B)=mean_uu, [256B,512B)=mean_iu ; item row r: [0,256B)=mean_ub
  // k_out waves read only their own rows' means (used values), then overwrite them.

  // workspace layout (37.1 MB), offsets in INTs:
  //   off 150016 | bhist 320 | cursor 320 | boff 320 | ebuf 1.8M | ssrc 900000 |
  //   WT 24576 | fb_u 3.2M | fb_i 3.2M  -> ends at 9,275,552 ints
  int* wsi    = (int*)d_ws;
  int* off    = wsi;                        // [150001] -> pad to 150016
  int* bhist  = wsi + 150016;               // [293] pad 320
  int* cursor = wsi + 150336;               // [293] pad 320
  int* boff   = wsi + 150656;               // [294] pad 320
  u32* ebuf   = (u32*)(wsi + 150976);       // [1800000] (7.2 MB)
  u16* ssrc   = (u16*)(wsi + 1950976);      // [1800000] u16 (3.6 MB)
  u16* WT     = (u16*)(wsi + 2850976);      // WTu 32768 + WTi 16384 u16 (96 KB)
  u16* fb_u   = (u16*)(wsi + 2875552);      // 50000x128 bf16 row-major (12.8 MB)
  u16* fb_i   = (u16*)(wsi + 6075552);      // 50000x128 bf16 row-major (12.8 MB)

  hipMemsetAsync(bhist, 0, 640 * sizeof(int), stream);   // bhist + cursor
  k_front<<<443, 256, 0, stream>>>(duu, dub, diu, bhist, Wuu, Wub, Wiu, WT);
  // conversion part 1 (782 filler blocks) overlaps edge placement
  k_bplace<<<440 + 782, 256, 0, stream>>>(suu, duu, sub, dub, siu, diu, bhist, cursor,
                                          boff, ebuf, fu, fi, fb_u, fb_i);
  // conversion part 2 (781 filler blocks) overlaps CSR finalize
  k_csr<<<NB + 781, 256, 0, stream>>>(boff, ebuf, off, ssrc, fu, fi, fb_u, fb_i);
  k_mean<<<18750, 256, 0, stream>>>(fb_u, fb_i, off, ssrc, ob);
  k_out<<<dim3(391, 2), 256, 0, stream>>>(out, WT, buu, bub, biu, off);
}

// Round 13
// 268.088 us; speedup vs baseline: 1.0627x; 1.0172x over previous
//
#include <hip/hip_runtime.h>
#include <stdint.h>
#include <string.h>

#define N_USER 50000
#define N_ITEM 50000
#define N_EDGE 600000
#define D 128
#define NTOT 150000      // 3 * 50000 destination slots (uu | ub | iu)
#define ETOT 1800000
#define NB 293           // buckets = ceil(NTOT / SPAN)
#define BSH 9
#define SPAN 512         // slots per bucket
#define CHUNK 4096       // edges per block in bucket kernels (16/thread)

typedef unsigned short u16;
typedef unsigned int   u32;
typedef __attribute__((ext_vector_type(8))) short short8;   // 8 bf16 (MFMA A/B frag)
typedef __attribute__((ext_vector_type(4))) float floatx4;  // MFMA C/D frag

static __device__ __forceinline__ u16 f2b(float f) {        // f32 -> bf16 RNE
  u32 x; memcpy(&x, &f, 4);
  u32 r = x + 0x7fffu + ((x >> 16) & 1u);
  return (u16)(r >> 16);
}
static __device__ __forceinline__ float blo2f(u32 v) {
  u32 x = v << 16; float f; memcpy(&f, &x, 4); return f;
}
static __device__ __forceinline__ float bhi2f(u32 v) {
  u32 x = v & 0xffff0000u; float f; memcpy(&f, &x, 4); return f;
}

// shared streaming f32->bf16 conversion body: 8 float4-groups per thread starting
// at group cbase. Total groups = 3.2M (fu then fi). Runs as filler blocks inside
// the under-utilized k_bplace/k_csr launches (440 / 293 real blocks on 256 CUs).
static __device__ __forceinline__ void conv_chunk(int cbase,
    const float* __restrict__ fu, const float* __restrict__ fi,
    u16* __restrict__ fb_u, u16* __restrict__ fb_i) {
#pragma unroll
  for (int u = 0; u < 8; ++u) {
    int gid = cbase + u * 256 + (int)threadIdx.x;
    if (gid < 3200000) {
      const float* src = fu; u16* dst = fb_u; int g = gid;
      if (g >= 1600000) { g -= 1600000; src = fi; dst = fb_i; }
      float4 v = ((const float4*)src)[g];
      union { u16 q[4]; uint2 d; } pk;
      pk.q[0] = f2b(v.x); pk.q[1] = f2b(v.y); pk.q[2] = f2b(v.z); pk.q[3] = f2b(v.w);
      ((uint2*)dst)[g] = pk.d;
    }
  }
}

// ---- front: [0,440) edge-bucket histogram | [440,443) weight transpose (stacked) ----
// WTu = [W_uu ; W_iu]^T as [n=128][k=256]; WTi = W_ub^T as [n=128][k=128] at +32768 u16.
__global__ void __launch_bounds__(256) k_front(
    const int* __restrict__ duu, const int* __restrict__ dub, const int* __restrict__ diu,
    int* __restrict__ bhist,
    const float* __restrict__ W0, const float* __restrict__ W1, const float* __restrict__ W2,
    u16* __restrict__ WT) {
  int bid = blockIdx.x;
  if (bid < 440) {                       // bucket histogram
    __shared__ int h[NB];
    for (int i = threadIdx.x; i < NB; i += 256) h[i] = 0;
    __syncthreads();
    int base = bid * CHUNK;
    for (int j = threadIdx.x; j < CHUNK; j += 256) {
      int e = base + j;
      if (e < ETOT) {
        int t = e / N_EDGE, i = e - t * N_EDGE;
        int d = (t == 0) ? duu[i] : ((t == 1) ? dub[i] : diu[i]);
        atomicAdd(&h[(t * N_USER + d) >> BSH], 1);
      }
    }
    __syncthreads();
    for (int i = threadIdx.x; i < NB; i += 256) if (h[i]) atomicAdd(&bhist[i], h[i]);
  } else {                               // weight transpose + bf16 (stacked layout)
    int wsel = bid - 440;
    for (int idx = threadIdx.x; idx < D * D; idx += 256) {
      int n = idx >> 7, k = idx & 127;
      if (wsel == 0)      WT[n * 256 + k]       = f2b(W0[k * D + n]);   // W_uu -> WTu k<128
      else if (wsel == 1) WT[n * 256 + 128 + k] = f2b(W2[k * D + n]);   // W_iu -> WTu k>=128
      else                WT[32768 + n * D + k] = f2b(W1[k * D + n]);   // W_ub -> WTi
    }
  }
}

// ---- place edges into bucket-grouped ebuf; blocks >=440 run feature conversion
//      (part 1: groups [0, 1601536)). Each placement block re-derives the bucket
//      scan from bhist; block 0 publishes boff ----
__global__ void __launch_bounds__(256) k_bplace(
    const int* __restrict__ suu, const int* __restrict__ duu,
    const int* __restrict__ sub, const int* __restrict__ dub,
    const int* __restrict__ siu, const int* __restrict__ diu,
    const int* __restrict__ bhist, int* __restrict__ cursor,
    int* __restrict__ boff, u32* __restrict__ ebuf,
    const float* __restrict__ fu, const float* __restrict__ fi,
    u16* __restrict__ fb_u, u16* __restrict__ fb_i) {
  if (blockIdx.x >= 440) {               // conversion filler (idle-CU work)
    conv_chunk((blockIdx.x - 440) * 2048, fu, fi, fb_u, fb_i);
    return;
  }
  __shared__ int h[NB];
  __shared__ int sboff[NB];
  __shared__ int buf[256];
  int t = threadIdx.x;
  int a = (2 * t < NB) ? bhist[2 * t] : 0;
  int b = (2 * t + 1 < NB) ? bhist[2 * t + 1] : 0;
  buf[t] = a + b; __syncthreads();
  for (int s = 1; s < 256; s <<= 1) {
    int y = (t >= s) ? buf[t - s] : 0;
    __syncthreads(); buf[t] += y; __syncthreads();
  }
  int ex = buf[t] - (a + b);                 // exclusive prefix of pair base
  if (2 * t < NB) sboff[2 * t] = ex;
  if (2 * t + 1 < NB) sboff[2 * t + 1] = ex + a;
  if (blockIdx.x == 0) {
    if (2 * t < NB) boff[2 * t] = ex;
    if (2 * t + 1 < NB) boff[2 * t + 1] = ex + a;
    if (t == 255) boff[NB] = buf[255];       // total = ETOT
  }
  for (int i = t; i < NB; i += 256) h[i] = 0;
  __syncthreads();
  int base = blockIdx.x * CHUNK;
  u32 pay[16], br[16];
#pragma unroll
  for (int k = 0; k < 16; ++k) {
    int e = base + k * 256 + t;
    br[k] = 0xFFFFFFFFu;
    if (e < ETOT) {
      int ty = e / N_EDGE, i = e - ty * N_EDGE;
      int d, s;
      if (ty == 0)      { d = duu[i]; s = suu[i]; }
      else if (ty == 1) { d = dub[i]; s = sub[i]; }
      else              { d = diu[i]; s = siu[i]; }
      int slot = ty * N_USER + d;
      int bu = slot >> BSH;
      int rank = atomicAdd(&h[bu], 1);
      pay[k] = (u32)s | ((u32)(slot & (SPAN - 1)) << 16);
      br[k]  = (u32)bu | ((u32)rank << 9);       // bu<=292 fits 9 bits; rank<4096
    }
  }
  __syncthreads();
  for (int i = t; i < NB; i += 256)
    h[i] = sboff[i] + atomicAdd(&cursor[i], h[i]);    // block base within bucket region
  __syncthreads();
#pragma unroll
  for (int k = 0; k < 16; ++k) {
    if (br[k] != 0xFFFFFFFFu) {
      int bu = br[k] & 0x1FF, rank = (int)(br[k] >> 9);
      ebuf[h[bu] + rank] = pay[k];
    }
  }
}

// ---- per-bucket CSR finalize (SPAN=512, 2 slots/thread); blocks >=293 run
//      feature conversion part 2 (groups [1601536, 3200000)) ----
__global__ void __launch_bounds__(256) k_csr(const int* __restrict__ boff, const u32* __restrict__ ebuf,
                                             int* __restrict__ off, u16* __restrict__ ssrc,
                                             const float* __restrict__ fu, const float* __restrict__ fi,
                                             u16* __restrict__ fb_u, u16* __restrict__ fb_i) {
  if (blockIdx.x >= NB) {                // conversion filler (idle-CU work)
    conv_chunk((blockIdx.x - NB) * 2048 + 1601536, fu, fi, fb_u, fb_i);
    return;
  }
  __shared__ int sc[SPAN];
  __shared__ int so[SPAN];
  __shared__ int part[256];
  int b = blockIdx.x;
  int ebase = boff[b], ecnt = boff[b + 1] - ebase;
  int sbase = b << BSH;
  int nslots = (NTOT - sbase < SPAN) ? (NTOT - sbase) : SPAN;
  for (int i = threadIdx.x; i < SPAN; i += 256) sc[i] = 0;
  __syncthreads();
  for (int j = threadIdx.x; j < ecnt; j += 256)
    atomicAdd(&sc[ebuf[ebase + j] >> 16], 1);
  __syncthreads();
  int t = threadIdx.x;
  int s0 = sc[2 * t], s1 = sc[2 * t + 1];
  int tsum = s0 + s1;
  part[t] = tsum; __syncthreads();
  for (int s = 1; s < 256; s <<= 1) {
    int y = (t >= s) ? part[t - s] : 0;
    __syncthreads(); part[t] += y; __syncthreads();
  }
  int pbase = part[t] - tsum;
  so[2 * t]     = pbase;
  so[2 * t + 1] = pbase + s0;
  __syncthreads();
  for (int i = threadIdx.x; i < nslots; i += 256)
    off[sbase + i] = ebase + so[i];
  if (b == 0 && threadIdx.x == 0) off[NTOT] = ETOT;
  for (int i = threadIdx.x; i < SPAN; i += 256) sc[i] = so[i];   // cursors
  __syncthreads();
  for (int j = threadIdx.x; j < ecnt; j += 256) {
    u32 p = ebuf[ebase + j];
    int pos = atomicAdd(&sc[p >> 16], 1);
    ssrc[ebase + pos] = (u16)(p & 0xFFFFu);
  }
}

// ---- gather-mean v5, split into two launches along the feature-table boundary
//      (slots <100000 read fb_u; slots >=100000 read fb_i) for per-kernel counter
//      visibility + L2 locality. Body = proven v3 + 8-deep MLP batch. ----
__global__ void __launch_bounds__(256) k_mean(const u16* __restrict__ fb_u, const u16* __restrict__ fb_i,
                                              const int* __restrict__ off, const u16* __restrict__ ssrc,
                                              u16* __restrict__ ob, int slot_base, int slot_lim) {
  int slot = slot_base + blockIdx.x * 8 + (threadIdx.x >> 5);
  int lane = threadIdx.x & 31;
  if (slot >= slot_lim) return;
  int t = slot / N_USER;
  int d = slot - t * N_USER;
  const u16* fb = (t == 2) ? fb_i : fb_u;
  int s = off[slot], e = off[slot + 1];
  int n = e - s;
  int my_src = (lane < n) ? (int)ssrc[s + lane] : 0;   // preload up to 32 edge srcs
  float a0 = 0.f, a1 = 0.f, a2 = 0.f, a3 = 0.f;
  int m = (n < 32) ? n : 32;
  int i = 0;
  for (; i + 8 <= m; i += 8) {
    int sA[8];
#pragma unroll
    for (int k = 0; k < 8; ++k) sA[k] = __shfl(my_src, i + k, 32);
    uint2 v[8];
#pragma unroll
    for (int k = 0; k < 8; ++k) v[k] = ((const uint2*)(fb + (size_t)sA[k] * D))[lane];
#pragma unroll
    for (int k = 0; k < 8; ++k) {
      a0 += blo2f(v[k].x); a1 += bhi2f(v[k].x);
      a2 += blo2f(v[k].y); a3 += bhi2f(v[k].y);
    }
  }
  for (; i + 4 <= m; i += 4) {
    int s0 = __shfl(my_src, i, 32);
    int s1 = __shfl(my_src, i + 1, 32);
    int s2 = __shfl(my_src, i + 2, 32);
    int s3 = __shfl(my_src, i + 3, 32);
    uint2 v0 = ((const uint2*)(fb + (size_t)s0 * D))[lane];
    uint2 v1 = ((const uint2*)(fb + (size_t)s1 * D))[lane];
    uint2 v2 = ((const uint2*)(fb + (size_t)s2 * D))[lane];
    uint2 v3 = ((const uint2*)(fb + (size_t)s3 * D))[lane];
    a0 += blo2f(v0.x) + blo2f(v1.x) + blo2f(v2.x) + blo2f(v3.x);
    a1 += bhi2f(v0.x) + bhi2f(v1.x) + bhi2f(v2.x) + bhi2f(v3.x);
    a2 += blo2f(v0.y) + blo2f(v1.y) + blo2f(v2.y) + blo2f(v3.y);
    a3 += bhi2f(v0.y) + bhi2f(v1.y) + bhi2f(v2.y) + bhi2f(v3.y);
  }
  for (; i < m; ++i) {
    int sr = __shfl(my_src, i, 32);
    uint2 v = ((const uint2*)(fb + (size_t)sr * D))[lane];
    a0 += blo2f(v.x); a1 += bhi2f(v.x);
    a2 += blo2f(v.y); a3 += bhi2f(v.y);
  }
  for (int j = s + 32; j < e; ++j) {     // rare degree>32 remainder
    int sr = ssrc[j];
    uint2 v = ((const uint2*)(fb + (size_t)sr * D))[lane];
    a0 += blo2f(v.x); a1 += bhi2f(v.x);
    a2 += blo2f(v.y); a3 += bhi2f(v.y);
  }
  float inv = (n > 0) ? 1.0f / (float)n : 0.f;
  u32 p0 = (u32)f2b(a0 * inv) | ((u32)f2b(a1 * inv) << 16);
  u32 p1 = (u32)f2b(a2 * inv) | ((u32)f2b(a3 * inv) << 16);
  u32* mrow;
  if (t == 0)      mrow = (u32*)(ob + (size_t)d * 256);              // mean_uu: row 1st half
  else if (t == 2) mrow = (u32*)(ob + (size_t)d * 256 + 128);        // mean_iu: row 2nd half
  else             mrow = (u32*)(ob + 12800000 + (size_t)d * 256);   // mean_ub: item row
  ((uint2*)mrow)[lane] = make_uint2(p0, p1);
}

// ---- final GEMM v5: LDS-staged B fragments + hoisted A/gate loads (r9) + NEW
//      coalesced epilogue: acc -> stride-132 LDS tile (aliasing sB after barrier)
//      -> float4 coalesced stores, in 2 half-tile passes (rt). ----
__global__ void __launch_bounds__(256, 2) k_out(float* out, const u16* __restrict__ WT,
                                                const float* __restrict__ buu, const float* __restrict__ bub,
                                                const float* __restrict__ biu, const int* __restrict__ off) {
  int users = (blockIdx.y == 0);
  int tid = threadIdx.x;
  int w = tid >> 6, lane = tid & 63, quad = lane >> 4, l16 = lane & 15;
  int KT = users ? 8 : 4;                        // K/32 tiles (K=256 user, 128 item)
  const u16* Wsrc = users ? WT : (WT + 32768);
  int wstride = users ? 256 : 128;               // u16 per WT row

  // stage B fragments: sB[((kk*8+nt)*64+lane)*8 u16] = 16B fragment for (kk,nt,lane)
  __shared__ u16 sB[32768];                      // 64 KB (user); item uses first 32 KB
  int nfrag = KT * 8 * 64;
  for (int fid = tid; fid < nfrag; fid += 256) {
    int fl = fid & 63, fnt = (fid >> 6) & 7, fkk = fid >> 9;
    int fq = fl >> 4, fl16 = fl & 15;
    const u16* src = Wsrc + (fnt * 16 + fl16) * wstride + fkk * 32 + fq * 8;
    *(uint4*)(sB + (size_t)fid * 8) = *(const uint4*)src;
  }

  int row0 = blockIdx.x * 128 + w * 32;          // wave's 32 rows (2 tiles of 16)
  const u16* ob = (const u16*)out;
  const u16* Abase = users ? ob : (ob + 12800000);
  size_t outoff = users ? 0 : (size_t)N_USER;

  int r0a = row0 + l16, r1a = row0 + 16 + l16;
  int rA0 = r0a < N_USER ? r0a : N_USER - 1;
  int rA1 = r1a < N_USER ? r1a : N_USER - 1;
  const u16* A0 = Abase + (size_t)rA0 * 256 + quad * 8;
  const u16* A1 = Abase + (size_t)rA1 * 256 + quad * 8;

  // hoist all A-fragment loads (issued before the barrier drains VMEM)
  short8 af0[8], af1[8];
#pragma unroll
  for (int kk = 0; kk < 8; ++kk) {
    if (kk < KT) {
      af0[kk] = *(const short8*)(A0 + kk * 32);
      af1[kk] = *(const short8*)(A1 + kk * 32);
    }
  }
  // hoist degree-gate loads too
  int nA[2][4], nB[2][4];
#pragma unroll
  for (int rt = 0; rt < 2; ++rt)
#pragma unroll
    for (int i = 0; i < 4; ++i) {
      int grow = row0 + rt * 16 + quad * 4 + i;
      bool ok = grow < N_USER;
      if (users) {
        nA[rt][i] = ok ? (off[grow + 1] - off[grow]) : 0;                             // uu
        nB[rt][i] = ok ? (off[2 * N_USER + grow + 1] - off[2 * N_USER + grow]) : 0;   // iu
      } else {
        nA[rt][i] = ok ? (off[N_USER + grow + 1] - off[N_USER + grow]) : 0;           // ub
        nB[rt][i] = 0;
      }
    }
  __syncthreads();

  floatx4 acc[2][8];
#pragma unroll
  for (int rt = 0; rt < 2; ++rt)
#pragma unroll
    for (int nt = 0; nt < 8; ++nt) acc[rt][nt] = (floatx4){0.f, 0.f, 0.f, 0.f};

#pragma unroll
  for (int kk = 0; kk < 8; ++kk) {
    if (kk < KT) {
      const short8* bp = (const short8*)(sB + ((size_t)kk * 512 + lane) * 8);
#pragma unroll
      for (int nt = 0; nt < 8; ++nt) {
        short8 bf = bp[nt * 64];
        acc[0][nt] = __builtin_amdgcn_mfma_f32_16x16x32_bf16(af0[kk], bf, acc[0][nt], 0, 0, 0);
        acc[1][nt] = __builtin_amdgcn_mfma_f32_16x16x32_bf16(af1[kk], bf, acc[1][nt], 0, 0, 0);
      }
    }
  }

  // coalesced epilogue: 2 half-tile passes; sO aliases sB (all ds_reads drained
  // by the barrier at the top of each pass; 64 rows x stride 132 = 33.8KB <= 64KB)
  float* sO = (float*)sB;
#pragma unroll
  for (int rt = 0; rt < 2; ++rt) {
    __syncthreads();                       // rt=0: B-reads done; rt=1: prior stores done
#pragma unroll
    for (int nt = 0; nt < 8; ++nt) {
      int col = nt * 16 + l16;
      float bA = users ? buu[col] : bub[col];
      float bB = users ? biu[col] : 0.f;
#pragma unroll
      for (int i = 0; i < 4; ++i) {
        float r = acc[rt][nt][i] + (nA[rt][i] > 0 ? bA : 0.f) + (nB[rt][i] > 0 ? bB : 0.f);
        sO[(w * 16 + quad * 4 + i) * 132 + col] = r;
      }
    }
    __syncthreads();
#pragma unroll
    for (int it = 0; it < 8; ++it) {       // 64 rows x 32 float4-groups, coalesced
      int idx = it * 256 + tid;
      int lr = idx >> 5, cg = (idx & 31) * 4;
      int grow = blockIdx.x * 128 + (lr >> 4) * 32 + rt * 16 + (lr & 15);
      if (grow < N_USER) {
        float4 v = make_float4(sO[lr * 132 + cg], sO[lr * 132 + cg + 1],
                               sO[lr * 132 + cg + 2], sO[lr * 132 + cg + 3]);
        *(float4*)(out + (outoff + (size_t)grow) * D + cg) = v;
      }
    }
  }
}

extern "C" void kernel_launch(void* const* d_in, const int* in_sizes, int n_in,
                              void* d_out, int out_size, void* d_ws, size_t ws_size,
                              hipStream_t stream) {
  const float* fu  = (const float*)d_in[0];
  const float* fi  = (const float*)d_in[1];
  const float* Wuu = (const float*)d_in[2];
  const float* buu = (const float*)d_in[3];
  const float* Wub = (const float*)d_in[4];
  const float* bub = (const float*)d_in[5];
  const float* Wiu = (const float*)d_in[6];
  const float* biu = (const float*)d_in[7];
  const int* suu = (const int*)d_in[8];
  const int* duu = (const int*)d_in[9];
  const int* sub = (const int*)d_in[10];
  const int* dub = (const int*)d_in[11];
  const int* siu = (const int*)d_in[12];
  const int* diu = (const int*)d_in[13];
  float* out = (float*)d_out;   // f32: [out_user 50000x128 | out_item 50000x128]
  u16* ob = (u16*)d_out;
  // d_out scratch (race-free): k_mean writes bf16 means INTO the output rows
  //   user row r: [0,256B)=mean_uu, [256B,512B)=mean_iu ; item row r: [0,256B)=mean_ub
  // k_out waves read only their own rows' means (used values), then overwrite them.

  // workspace layout (37.1 MB), offsets in INTs:
  //   off 150016 | bhist 320 | cursor 320 | boff 320 | ebuf 1.8M | ssrc 900000 |
  //   WT 24576 | fb_u 3.2M | fb_i 3.2M  -> ends at 9,275,552 ints
  int* wsi    = (int*)d_ws;
  int* off    = wsi;                        // [150001] -> pad to 150016
  int* bhist  = wsi + 150016;               // [293] pad 320
  int* cursor = wsi + 150336;               // [293] pad 320
  int* boff   = wsi + 150656;               // [294] pad 320
  u32* ebuf   = (u32*)(wsi + 150976);       // [1800000] (7.2 MB)
  u16* ssrc   = (u16*)(wsi + 1950976);      // [1800000] u16 (3.6 MB)
  u16* WT     = (u16*)(wsi + 2850976);      // WTu 32768 + WTi 16384 u16 (96 KB)
  u16* fb_u   = (u16*)(wsi + 2875552);      // 50000x128 bf16 row-major (12.8 MB)
  u16* fb_i   = (u16*)(wsi + 6075552);      // 50000x128 bf16 row-major (12.8 MB)

  hipMemsetAsync(bhist, 0, 640 * sizeof(int), stream);   // bhist + cursor
  k_front<<<443, 256, 0, stream>>>(duu, dub, diu, bhist, Wuu, Wub, Wiu, WT);
  // conversion part 1 (782 filler blocks) overlaps edge placement
  k_bplace<<<440 + 782, 256, 0, stream>>>(suu, duu, sub, dub, siu, diu, bhist, cursor,
                                          boff, ebuf, fu, fi, fb_u, fb_i);
  // conversion part 2 (781 filler blocks) overlaps CSR finalize
  k_csr<<<NB + 781, 256, 0, stream>>>(boff, ebuf, off, ssrc, fu, fi, fb_u, fb_i);
  // user-table slots (uu+ub, 1.2M edges) then item-table slots (iu, 0.6M edges)
  k_mean<<<12500, 256, 0, stream>>>(fb_u, fb_i, off, ssrc, ob, 0, 100000);
  k_mean<<<6250, 256, 0, stream>>>(fb_u, fb_i, off, ssrc, ob, 100000, NTOT);
  k_out<<<dim3(391, 2), 256, 0, stream>>>(out, WT, buu, bub, biu, off);
}